// Round 10
// baseline (188.039 us; speedup 1.0000x reference)
//
#include <hip/hip_runtime.h>
#include <hip/hip_bf16.h>
#include <cstdint>
#include <cstddef>

using u16 = unsigned short;
using u32 = uint32_t;
using f32x4  = __attribute__((ext_vector_type(4))) float;
using bf16x8 = __attribute__((ext_vector_type(8))) __bf16;
using s16x4  = __attribute__((ext_vector_type(4))) short;   // 4 bf16 raw bits

#define D_MODEL 1024
#define N_HEADS 16
#define HD      64
#define SEQ     2048
#define QKV_LD  3072   // 3*D_MODEL, row stride of qkv
#define K2SCALE 0.18033688011112042f   // 0.125 * log2(e), folded into Q

// ---------- helpers ----------
__device__ __forceinline__ u16 f2b(float f) {           // fp32 -> bf16 RNE
  union { float f; u32 u; } v; v.f = f;
  u32 r = 0x7FFFu + ((v.u >> 16) & 1u);
  return (u16)((v.u + r) >> 16);
}

// packed pair via v_cvt_pk_bf16_f32 (gfx950); a->lo16, b->hi16
__device__ __forceinline__ u32 pkbf16(float a, float b) {
  union { __hip_bfloat162 h; u32 u; } c;
  c.h = __float22bfloat162_rn(float2{a, b});
  return c.u;
}

// NOTE: do NOT gate amdgcn builtins on __has_builtin (false on host pass).
#define MFMA16(A, B, C) __builtin_amdgcn_mfma_f32_16x16x16bf16_1k(A, B, C, 0, 0, 0)

__device__ __forceinline__ void gld16(const void* g, u16* l) {
  // async global->LDS, 16B per lane; LDS dest = wave-uniform base + lane*16
  __builtin_amdgcn_global_load_lds(
      (const __attribute__((address_space(1))) void*)g,
      (__attribute__((address_space(3))) void*)l, 16, 0, 0);
}

// ---------- fp32 -> bf16 cast of w_qkv | w_proj (dst contiguous) ----------
// x-cast is FUSED into the qkv GEMM's A staging (R10): only weights here.
__global__ void cast2_bf16(const float* __restrict__ wq, const float* __restrict__ wp,
                           u16* __restrict__ dst) {
  int i = blockIdx.x * blockDim.x + threadIdx.x;        // float4 index
  const float* src;
  int off;
  if (blockIdx.x < 3072) { src = wq; off = 0; }
  else                   { src = wp; off = 3072 * 256; }
  float4 f = ((const float4*)src)[i - off];
  u32 lo = pkbf16(f.x, f.y), hi = pkbf16(f.z, f.w);
  uint2 o = {lo, hi};
  ((uint2*)dst)[i] = o;
}

// ---------- NT GEMM: C[M,N] = A[M,K] * B[N,K]^T  (fp32 acc) ----------
// Single-barrier pipelined K-loop (R6 champion form — R8 proved 256² deep
// pipeline loses at this shape). MT = M-tile; N-tile fixed 128.
// AF32: A operand is raw fp32 (x) staged directly via global_load_lds and
// converted to bf16 in-register after ds_read (fused cast; same RNE cvt as
// the old cast kernel -> numerics identical). fp32 A rows = 128B natural, so
// the chunk^(row&7) swizzle applies per-row; reads stay 2-way (free).
// !AF32: bf16 A, two BK=32 rows per 128B line, chunk^(line&7) swizzle.
// Staging is LDS-linear with pre-swizzled global source (rule #21).
// OUTMODE 0: bf16 out, cols < D_MODEL pre-scaled by K2SCALE. 1: fp32 + bias.
// XCD-bijective block swizzle (T1); nwg % 8 == 0 for our grids.
template<int OUTMODE, int MT, int AF32>
__launch_bounds__(256, 3)
__global__ void gemm_nt(const void* __restrict__ Av, const u16* __restrict__ B,
                        u16* __restrict__ Ob, float* __restrict__ Of,
                        const float* __restrict__ bias, int N, int K) {
  __shared__ __attribute__((aligned(16))) u16 sA[2][MT * 32 * (AF32 ? 2 : 1)];
  __shared__ __attribute__((aligned(16))) u16 sB[2][128 * 32];

  const float* Af = (const float*)Av;
  const u16*   Ab = (const u16*)Av;

  const int tid  = threadIdx.x;
  const int lane = tid & 63;
  const int w    = tid >> 6;
  const int qd   = lane >> 4;      // quad 0..3
  const int ln   = lane & 15;
  constexpr int MI = MT / 32;      // m-subtiles per wave (4 or 2)
  const int wm   = (w >> 1) * (MT / 2);
  const int wn   = (w & 1) * 64;

  // XCD-aware block swizzle (dispatch order: blockIdx.x fastest)
  const int nbx = gridDim.x;
  const int lin = blockIdx.y * nbx + blockIdx.x;
  const int cpx = (nbx * gridDim.y) >> 3;
  const int swz = (lin & 7) * cpx + (lin >> 3);
  const int m0  = (swz / nbx) * MT;
  const int n0  = (swz % nbx) * 128;

  auto stage = [&](int kk, int buf) {
    int k0 = kk * 32;
    if constexpr (AF32) {
      // A fp32: MT x 32 f32 = MT*8 slots; row = 8 chunks of 16B (4 f32)
      #pragma unroll
      for (int c = 0; c < MT / 32; ++c) {
        int sbase = c * 256 + w * 64;        // wave-uniform slot base
        int s = sbase + lane;
        int row = s >> 3, ch = (s & 7) ^ (row & 7);   // pre-swizzled source
        gld16(Af + (size_t)(m0 + row) * K + k0 + ch * 4, &sA[buf][sbase * 8]);
      }
    } else {
      #pragma unroll
      for (int c = 0; c < MT / 64; ++c) {    // A bf16, 16B/lane
        int sbase = w * MT + c * 64;
        int s = sbase + lane;
        int line = s >> 3, sub = (s & 7) ^ (line & 7);
        int row = line * 2 + (sub >> 2), col = (sub & 3) * 8;
        gld16(Ab + (size_t)(m0 + row) * K + k0 + col, &sA[buf][sbase * 8]);
      }
    }
    #pragma unroll
    for (int c = 0; c < 2; ++c) {            // B (bf16)
      int sbase = w * 128 + c * 64;
      int s = sbase + lane;
      int line = s >> 3, sub = (s & 7) ^ (line & 7);
      int row = line * 2 + (sub >> 2), col = (sub & 3) * 8;
      gld16(B + (size_t)(n0 + row) * K + k0 + col, &sB[buf][sbase * 8]);
    }
  };

  f32x4 acc[MI][4] = {};
  const int NK = K >> 5;
  stage(0, 0);

  for (int kk = 0; kk < NK; ++kk) {
    const int cur = kk & 1;
    __syncthreads();
    if (kk + 1 < NK) stage(kk + 1, cur ^ 1);

    bf16x8 af[MI], bfm[4];
    #pragma unroll
    for (int i = 0; i < MI; ++i) {
      int r = wm + i * 16 + ln;
      if constexpr (AF32) {
        // global chunks 2qd, 2qd+1 of row r live at LDS pos ch^(r&7)
        const float* sAf = (const float*)sA[cur];
        f32x4 lo = *(const f32x4*)&sAf[r * 32 + (((2 * qd    ) ^ (r & 7)) << 2)];
        f32x4 hi = *(const f32x4*)&sAf[r * 32 + (((2 * qd + 1) ^ (r & 7)) << 2)];
        union { u32 d[4]; bf16x8 v; } u;
        u.d[0] = pkbf16(lo[0], lo[1]);
        u.d[1] = pkbf16(lo[2], lo[3]);
        u.d[2] = pkbf16(hi[0], hi[1]);
        u.d[3] = pkbf16(hi[2], hi[3]);
        af[i] = u.v;
      } else {
        af[i] = *(const bf16x8*)&sA[cur][(r >> 1) * 64 +
                  ((((r & 1) << 5) + qd * 8) ^ (((r >> 1) & 7) << 3))];
      }
    }
    #pragma unroll
    for (int j = 0; j < 4; ++j) {
      int r = wn + j * 16 + ln;
      bfm[j] = *(const bf16x8*)&sB[cur][(r >> 1) * 64 +
                ((((r & 1) << 5) + qd * 8) ^ (((r >> 1) & 7) << 3))];
    }
    #pragma unroll
    for (int i = 0; i < MI; ++i)
      #pragma unroll
      for (int j = 0; j < 4; ++j)
        acc[i][j] = __builtin_amdgcn_mfma_f32_16x16x32_bf16(af[i], bfm[j], acc[i][j], 0, 0, 0);
  }

  // epilogue: C/D layout col=lane&15, row=quad*4+reg
  #pragma unroll
  for (int i = 0; i < MI; ++i) {
    #pragma unroll
    for (int j = 0; j < 4; ++j) {
      #pragma unroll
      for (int r = 0; r < 4; ++r) {
        int row = m0 + wm + i * 16 + qd * 4 + r;
        int col = n0 + wn + j * 16 + ln;
        float v = acc[i][j][r];
        if (OUTMODE == 0) {
          if (col < D_MODEL) v *= K2SCALE;   // uniform per block (n0 mult of 128)
          Ob[(size_t)row * N + col] = f2b(v);
        } else {
          Of[(size_t)row * N + col] = v + bias[col];
        }
      }
    }
  }
}

// ---------- flash attention: R6 champion + XCD 1-D grid (setprio removed) ----------
// R1 wave structure (4 waves x 2 chains, 256 threads) + cross-tile software
// pipeline (QK^T(t) overlapped with finish(t-1); stA/stB ping-pong, 3-deep
// V LDS ring). 1-D grid bid = qp*32 + bh: all 16 Q-blocks of a (b,h) share an
// XCD -> K/V fetched once per XCD (R9-measured: FETCH 69.7 -> 12.4 MB).
// setprio dropped: null twice (R4, R9) on this structure.
__launch_bounds__(256, 2)
__global__ void attn_kernel(const u16* __restrict__ qkv, u16* __restrict__ outb) {
  // pool: sK 2x8KB @0 + sVT 3x8KB @16KB = 40 KB; epilogue reuses 18 KB
  __shared__ __attribute__((aligned(16))) u16 smem[20480];
  u16 (*sK)[64 * 64] = (u16(*)[64 * 64])smem;             // [buf 0..1], swizzled
  u32* const sVT0 = (u32*)(smem + 8192);                  // 3 x 2048 u32
  u32* const sVT1 = sVT0 + 64 * 32;
  u32* const sVT2 = sVT1 + 64 * 32;

  const int tid  = threadIdx.x;
  const int lane = tid & 63;
  const int w    = tid >> 6;              // 0..3
  const int qd   = lane >> 4;
  const int ln   = lane & 15;
  const int bid  = blockIdx.x;            // 0..511
  const int qp   = bid >> 5;              // 0..15, 128-row Q tile
  const int bh   = bid & 31;              // same-bh blocks share an XCD
  const int h    = bh & 15;
  const int b    = bh >> 4;
  const size_t tokbase = (size_t)b * SEQ;
  const int q0   = qp * 128;
  const int qoff = h * HD;
  const int koff = D_MODEL + h * HD;
  const int voff = 2 * D_MODEL + h * HD;

  // Q fragments: 2 chains (q-rows q0+c2*64+w*16+ln), B-operand layout
  bf16x8 aq[2][2];
  #pragma unroll
  for (int c2 = 0; c2 < 2; ++c2)
    #pragma unroll
    for (int hf = 0; hf < 2; ++hf)
      aq[c2][hf] = *(const bf16x8*)(qkv + (tokbase + q0 + c2 * 64 + w * 16 + ln) * QKV_LD
                                    + qoff + hf * 32 + qd * 8);

  auto stageK = [&](int kt, int buf) {
    #pragma unroll
    for (int c = 0; c < 2; ++c) {
      int sbase = c * 256 + w * 64;        // wave-uniform slot base
      int s = sbase + lane;
      int row = s >> 3, sub = (s & 7) ^ (row & 7);   // pre-swizzled source
      gld16(qkv + (tokbase + kt * 64 + row) * QKV_LD + koff + sub * 8,
            &sK[buf][sbase * 8]);
    }
  };
  auto loadV = [&](int kt, uint4& va, uint4& vb) {
    int tp = tid & 31, d0 = (tid >> 5) * 8;
    const u16* g0 = qkv + (tokbase + kt * 64 + tp * 2) * QKV_LD + voff + d0;
    va = *(const uint4*)g0;
    vb = *(const uint4*)(g0 + QKV_LD);
  };
  auto writeV = [&](u32* vbuf, const uint4& va, const uint4& vb) {
    int tp = tid & 31, d0 = (tid >> 5) * 8;  // d0 multiple of 8
    const u32* a  = (const u32*)&va;
    const u32* bb = (const u32*)&vb;
    #pragma unroll
    for (int e = 0; e < 4; ++e) {
      vbuf[(d0 + 2 * e    ) * 32 + (tp ^ (e << 3)    )] =
          __builtin_amdgcn_perm(bb[e], a[e], 0x05040100u);
      vbuf[(d0 + 2 * e + 1) * 32 + (tp ^ (e << 3) ^ 4)] =
          __builtin_amdgcn_perm(bb[e], a[e], 0x07060302u);
    }
  };

  f32x4 accOT[2][4] = {};          // O^T per chain: row d=ob*16+qd*4+r, col=ln
  f32x4 stA[4][2], stB[4][2];      // pipelined QK^T results (2 tiles in flight)
  float psum[2] = {0.f, 0.f};
  const int tsw = (ln & 7) << 2;   // sVT read-side XOR swizzle (u32 units)
  const int ksw = (ln & 7) << 3;   // sK read-side XOR swizzle (u16 units)

  auto qk_phase = [&](int t, f32x4 (&stW)[4][2]) {
    const int cur = t & 1;
    #pragma unroll
    for (int cb = 0; cb < 4; ++cb) {
      bf16x8 ak0 = *(const bf16x8*)&sK[cur][(cb * 16 + ln) * 64 + ((qd * 8) ^ ksw)];
      bf16x8 ak1 = *(const bf16x8*)&sK[cur][(cb * 16 + ln) * 64 + ((32 + qd * 8) ^ ksw)];
      #pragma unroll
      for (int c2 = 0; c2 < 2; ++c2) {
        f32x4 z = {0.f, 0.f, 0.f, 0.f};
        f32x4 t0 = __builtin_amdgcn_mfma_f32_16x16x32_bf16(ak0, aq[c2][0], z, 0, 0, 0);
        stW[cb][c2] = __builtin_amdgcn_mfma_f32_16x16x32_bf16(ak1, aq[c2][1], t0, 0, 0, 0);
      }
    }
  };
  auto fin_phase = [&](f32x4 (&stR)[4][2], const u32* vP) {
    #pragma unroll
    for (int cb = 0; cb < 4; ++cb) {
      s16x4 pf[2];
      #pragma unroll
      for (int c2 = 0; c2 < 2; ++c2) {
        float p0 = __builtin_amdgcn_exp2f(stR[cb][c2][0]);
        float p1 = __builtin_amdgcn_exp2f(stR[cb][c2][1]);
        float p2 = __builtin_amdgcn_exp2f(stR[cb][c2][2]);
        float p3 = __builtin_amdgcn_exp2f(stR[cb][c2][3]);
        psum[c2] += (p0 + p1) + (p2 + p3);
        union { u32 d[2]; s16x4 v; } pk;
        pk.d[0] = pkbf16(p0, p1);        // v_cvt_pk_bf16_f32
        pk.d[1] = pkbf16(p2, p3);
        pf[c2] = pk.v;
      }
      #pragma unroll
      for (int ob = 0; ob < 4; ++ob) {
        s16x4 vf = *(const s16x4*)&vP[(ob * 16 + ln) * 32 + ((cb * 8 + qd * 2) ^ tsw)];
        accOT[0][ob] = MFMA16(vf, pf[0], accOT[0][ob]);
        accOT[1][ob] = MFMA16(vf, pf[1], accOT[1][ob]);
      }
    }
  };

  // prologue: K(0) async; V(0) -> ring buf0; V(1) -> regs
  stageK(0, 0);
  uint4 va, vb;
  loadV(0, va, vb);
  writeV(sVT0, va, vb);
  loadV(1, va, vb);
  u32 *vPrev = sVT2, *vCur = sVT0, *vNext = sVT1;

  // t = 0 (no finish)
  __syncthreads();
  stageK(1, 1);
  writeV(vNext, va, vb);      // V(1)
  loadV(2, va, vb);
  qk_phase(0, stA);
  { u32* t = vPrev; vPrev = vCur; vCur = vNext; vNext = t; }

  // t = 1..30 in ping-pong pairs
  for (int S = 0; S < 15; ++S) {
    const int t1 = 2 * S + 1;
    __syncthreads();
    stageK(t1 + 1, (t1 + 1) & 1);
    writeV(vNext, va, vb);    // V(t1+1)
    loadV(t1 + 2, va, vb);    // t1 <= 29 -> t1+2 <= 31, always valid
    qk_phase(t1, stB);
    fin_phase(stA, vPrev);
    { u32* t = vPrev; vPrev = vCur; vCur = vNext; vNext = t; }
    const int t2 = t1 + 1;
    __syncthreads();
    stageK(t2 + 1, (t2 + 1) & 1);
    writeV(vNext, va, vb);    // V(t2+1)
    if (t2 < 30) loadV(t2 + 2, va, vb);
    qk_phase(t2, stA);
    fin_phase(stB, vPrev);
    { u32* t = vPrev; vPrev = vCur; vCur = vNext; vNext = t; }
  }

  // t = 31: QK -> stB, finish stA; then drain finish(31)
  __syncthreads();
  qk_phase(31, stB);
  fin_phase(stA, vPrev);      // tile 30
  fin_phase(stB, vCur);       // tile 31 (V(31) in vCur)

  // row-sum completion: reduce across the 4 quads
  #pragma unroll
  for (int c2 = 0; c2 < 2; ++c2) {
    float s = psum[c2];
    s += __shfl_xor(s, 16, 64);
    s += __shfl_xor(s, 32, 64);
    psum[c2] = 1.0f / s;
  }

  // transpose O^T -> O through LDS (reuse smem), coalesced bf16 stores
  u16* sOut = smem;                      // [128 tokens][72] u16 = 18 KB
  __syncthreads();
  #pragma unroll
  for (int c2 = 0; c2 < 2; ++c2)
    #pragma unroll
    for (int ob = 0; ob < 4; ++ob) {
      u32 lo = pkbf16(accOT[c2][ob][0] * psum[c2], accOT[c2][ob][1] * psum[c2]);
      u32 hi = pkbf16(accOT[c2][ob][2] * psum[c2], accOT[c2][ob][3] * psum[c2]);
      ((u32*)sOut)[(c2 * 64 + w * 16 + ln) * 36 + ob * 8 + qd * 2    ] = lo;
      ((u32*)sOut)[(c2 * 64 + w * 16 + ln) * 36 + ob * 8 + qd * 2 + 1] = hi;
    }
  __syncthreads();
  #pragma unroll
  for (int it = 0; it < 4; ++it) {
    int idx = it * 256 + tid;            // 0..1023
    int token = idx >> 3, chunk = idx & 7;
    uint4 v = *(const uint4*)&sOut[token * 72 + chunk * 8];
    *(uint4*)&outb[(tokbase + q0 + token) * D_MODEL + h * HD + chunk * 8] = v;
  }
}

// ---------- launch ----------
extern "C" void kernel_launch(void* const* d_in, const int* in_sizes, int n_in,
                              void* d_out, int out_size, void* d_ws, size_t ws_size,
                              hipStream_t stream) {
  const float* x      = (const float*)d_in[0];   // [4096,1024]
  const float* w_qkv  = (const float*)d_in[1];   // [3072,1024]
  const float* w_proj = (const float*)d_in[2];   // [1024,1024]
  const float* b_proj = (const float*)d_in[3];   // [1024]
  float* out = (float*)d_out;                    // [4096,1024]

  u16* ws     = (u16*)d_ws;
  u16* wqkvb  = ws;                                   // 3072*1024
  u16* wprojb = wqkvb + (size_t)3072 * 1024;          // 1024*1024
  u16* qkvb   = wprojb + (size_t)1024 * 1024;         // 4096*3072
  u16* attnb  = qkvb  + (size_t)4096 * 3072;          // 4096*1024

  // weights cast only (x-cast fused into qkv GEMM A-staging)
  cast2_bf16<<<4096, 256, 0, stream>>>(w_qkv, w_proj, wqkvb);

  // qkv = x @ w_qkv^T -> [4096,3072] bf16 (Q pre-scaled); A = fp32 x staged
  // directly (fused cast); 768 blocks = 3/CU
  gemm_nt<0, 128, 1><<<dim3(24, 32), 256, 0, stream>>>(x, wqkvb, qkvb, nullptr, nullptr, 3072, 1024);

  // attention -> [4096,1024] bf16; 512 blocks x 256 threads, 2/CU
  // 1-D grid: bid = qp*32 + bh so all qp-blocks of a (b,h) share an XCD
  attn_kernel<<<512, 256, 0, stream>>>(qkvb, attnb);

  // out = attn @ w_proj^T + b_proj -> fp32; 64x128 tiles, 512 blocks
  gemm_nt<1, 64, 0><<<dim3(8, 64), 256, 0, stream>>>(attnb, wprojb, nullptr, out, b_proj, 1024, 1024);
}

// Round 11
// 181.093 us; speedup vs baseline: 1.0384x; 1.0384x over previous
//
#include <hip/hip_runtime.h>
#include <hip/hip_bf16.h>
#include <cstdint>
#include <cstddef>

using u16 = unsigned short;
using u32 = uint32_t;
using f32x4  = __attribute__((ext_vector_type(4))) float;
using bf16x8 = __attribute__((ext_vector_type(8))) __bf16;
using s16x4  = __attribute__((ext_vector_type(4))) short;   // 4 bf16 raw bits

#define D_MODEL 1024
#define N_HEADS 16
#define HD      64
#define SEQ     2048
#define QKV_LD  3072   // 3*D_MODEL, row stride of qkv
#define K2SCALE 0.18033688011112042f   // 0.125 * log2(e), folded into Q

// ---------- helpers ----------
__device__ __forceinline__ u16 f2b(float f) {           // fp32 -> bf16 RNE
  union { float f; u32 u; } v; v.f = f;
  u32 r = 0x7FFFu + ((v.u >> 16) & 1u);
  return (u16)((v.u + r) >> 16);
}

// packed pair via v_cvt_pk_bf16_f32 (gfx950); a->lo16, b->hi16
__device__ __forceinline__ u32 pkbf16(float a, float b) {
  union { __hip_bfloat162 h; u32 u; } c;
  c.h = __float22bfloat162_rn(float2{a, b});
  return c.u;
}

// NOTE: do NOT gate amdgcn builtins on __has_builtin (false on host pass).
#define MFMA16(A, B, C) __builtin_amdgcn_mfma_f32_16x16x16bf16_1k(A, B, C, 0, 0, 0)

__device__ __forceinline__ void gld16(const u16* g, u16* l) {
  // async global->LDS, 16B per lane; LDS dest = wave-uniform base + lane*16
  __builtin_amdgcn_global_load_lds(
      (const __attribute__((address_space(1))) void*)g,
      (__attribute__((address_space(3))) void*)l, 16, 0, 0);
}

// ---------- fused fp32 -> bf16 cast of x, w_qkv, w_proj (dst contiguous) ----
// R10 lesson: fusing the x-cast into the qkv GEMM A-path costs ~8 us of GEMM
// (extra ds_read+cvt on the fragment critical path) to save ~4 us here.
// The standalone cast is the better trade — keep it.
__global__ void cast3_bf16(const float* __restrict__ x, const float* __restrict__ wq,
                           const float* __restrict__ wp, u16* __restrict__ dst) {
  int i = blockIdx.x * blockDim.x + threadIdx.x;        // float4 index
  const float* src;
  int off;
  if (blockIdx.x < 4096)      { src = x;  off = 0; }
  else if (blockIdx.x < 7168) { src = wq; off = 4096 * 256; }
  else                        { src = wp; off = 7168 * 256; }
  float4 f = ((const float4*)src)[i - off];
  u32 lo = pkbf16(f.x, f.y), hi = pkbf16(f.z, f.w);
  uint2 o = {lo, hi};
  ((uint2*)dst)[i] = o;
}

// ---------- NT GEMM (champion form): C[M,N] = A[M,K] * B[N,K]^T ----------
// Single-barrier pipelined K-loop. MT = M-tile (128 or 64); N-tile fixed 128.
// OUTMODE 0: bf16 out, cols < D_MODEL pre-scaled by K2SCALE.  1: fp32 + bias.
// LDS: two BK=32 rows per 128B line, chunk ^ (line&7) swizzle, linear staging
// with pre-swizzled global source (rule #21). XCD-bijective block swizzle (T1).
// Bracketed alternatives (all measured worse at this shape): 256² deep
// pipeline (R8, grid underfill), fused fp32-A cast (R10, fragment-path cost).
template<int OUTMODE, int MT>
__launch_bounds__(256, 3)
__global__ void gemm_nt(const u16* __restrict__ A, const u16* __restrict__ B,
                        u16* __restrict__ Ob, float* __restrict__ Of,
                        const float* __restrict__ bias, int N, int K) {
  __shared__ __attribute__((aligned(16))) u16 sA[2][MT * 32];
  __shared__ __attribute__((aligned(16))) u16 sB[2][128 * 32];

  const int tid  = threadIdx.x;
  const int lane = tid & 63;
  const int w    = tid >> 6;
  const int qd   = lane >> 4;      // quad 0..3
  const int ln   = lane & 15;
  constexpr int MI = MT / 32;      // m-subtiles per wave (4 or 2)
  const int wm   = (w >> 1) * (MT / 2);
  const int wn   = (w & 1) * 64;

  // XCD-aware block swizzle (dispatch order: blockIdx.x fastest)
  const int nbx = gridDim.x;
  const int lin = blockIdx.y * nbx + blockIdx.x;
  const int cpx = (nbx * gridDim.y) >> 3;        // nwg % 8 == 0 for our grids
  const int swz = (lin & 7) * cpx + (lin >> 3);
  const int m0  = (swz / nbx) * MT;
  const int n0  = (swz % nbx) * 128;

  auto stage = [&](int kk, int buf) {
    int k0 = kk * 32;
    #pragma unroll
    for (int c = 0; c < MT / 64; ++c) {      // A, 16B/lane
      int sbase = w * MT + c * 64;           // 16B-slot base (wave-uniform)
      int s = sbase + lane;
      int line = s >> 3, sub = (s & 7) ^ (line & 7);   // pre-swizzled source
      int row = line * 2 + (sub >> 2), col = (sub & 3) * 8;
      gld16(A + (size_t)(m0 + row) * K + k0 + col, &sA[buf][sbase * 8]);
    }
    #pragma unroll
    for (int c = 0; c < 2; ++c) {            // B
      int sbase = w * 128 + c * 64;
      int s = sbase + lane;
      int line = s >> 3, sub = (s & 7) ^ (line & 7);
      int row = line * 2 + (sub >> 2), col = (sub & 3) * 8;
      gld16(B + (size_t)(n0 + row) * K + k0 + col, &sB[buf][sbase * 8]);
    }
  };

  f32x4 acc[MI][4] = {};
  const int NK = K >> 5;
  stage(0, 0);

  for (int kk = 0; kk < NK; ++kk) {
    const int cur = kk & 1;
    __syncthreads();
    if (kk + 1 < NK) stage(kk + 1, cur ^ 1);

    bf16x8 af[MI], bfm[4];
    #pragma unroll
    for (int i = 0; i < MI; ++i) {
      int r = wm + i * 16 + ln;
      af[i] = *(const bf16x8*)&sA[cur][(r >> 1) * 64 +
                ((((r & 1) << 5) + qd * 8) ^ (((r >> 1) & 7) << 3))];
    }
    #pragma unroll
    for (int j = 0; j < 4; ++j) {
      int r = wn + j * 16 + ln;
      bfm[j] = *(const bf16x8*)&sB[cur][(r >> 1) * 64 +
                ((((r & 1) << 5) + qd * 8) ^ (((r >> 1) & 7) << 3))];
    }
    #pragma unroll
    for (int i = 0; i < MI; ++i)
      #pragma unroll
      for (int j = 0; j < 4; ++j)
        acc[i][j] = __builtin_amdgcn_mfma_f32_16x16x32_bf16(af[i], bfm[j], acc[i][j], 0, 0, 0);
  }

  // epilogue: C/D layout col=lane&15, row=quad*4+reg
  #pragma unroll
  for (int i = 0; i < MI; ++i) {
    #pragma unroll
    for (int j = 0; j < 4; ++j) {
      #pragma unroll
      for (int r = 0; r < 4; ++r) {
        int row = m0 + wm + i * 16 + qd * 4 + r;
        int col = n0 + wn + j * 16 + ln;
        float v = acc[i][j][r];
        if (OUTMODE == 0) {
          if (col < D_MODEL) v *= K2SCALE;   // uniform per block (n0 mult of 128)
          Ob[(size_t)row * N + col] = f2b(v);
        } else {
          Of[(size_t)row * N + col] = v + bias[col];
        }
      }
    }
  }
}

// ---------- flash attention: champion (R6 pipeline + 1-D XCD grid) ----------
// R1 wave structure (4 waves x 2 chains, 256 threads) + cross-tile software
// pipeline (QK^T(t) overlapped with finish(t-1); stA/stB ping-pong, 3-deep
// V LDS ring). 1-D grid bid = qp*32 + bh: all 16 Q-blocks of a (b,h) share an
// XCD -> K/V fetched once per XCD (measured: FETCH 69.7 -> 12.4 MB, time-
// neutral). setprio omitted (null twice: R4, R9).
__launch_bounds__(256, 2)
__global__ void attn_kernel(const u16* __restrict__ qkv, u16* __restrict__ outb) {
  // pool: sK 2x8KB @0 + sVT 3x8KB @16KB = 40 KB; epilogue reuses 18 KB
  __shared__ __attribute__((aligned(16))) u16 smem[20480];
  u16 (*sK)[64 * 64] = (u16(*)[64 * 64])smem;             // [buf 0..1], swizzled
  u32* const sVT0 = (u32*)(smem + 8192);                  // 3 x 2048 u32
  u32* const sVT1 = sVT0 + 64 * 32;
  u32* const sVT2 = sVT1 + 64 * 32;

  const int tid  = threadIdx.x;
  const int lane = tid & 63;
  const int w    = tid >> 6;              // 0..3
  const int qd   = lane >> 4;
  const int ln   = lane & 15;
  const int bid  = blockIdx.x;            // 0..511
  const int qp   = bid >> 5;              // 0..15, 128-row Q tile
  const int bh   = bid & 31;              // same-bh blocks share an XCD
  const int h    = bh & 15;
  const int b    = bh >> 4;
  const size_t tokbase = (size_t)b * SEQ;
  const int q0   = qp * 128;
  const int qoff = h * HD;
  const int koff = D_MODEL + h * HD;
  const int voff = 2 * D_MODEL + h * HD;

  // Q fragments: 2 chains (q-rows q0+c2*64+w*16+ln), B-operand layout
  bf16x8 aq[2][2];
  #pragma unroll
  for (int c2 = 0; c2 < 2; ++c2)
    #pragma unroll
    for (int hf = 0; hf < 2; ++hf)
      aq[c2][hf] = *(const bf16x8*)(qkv + (tokbase + q0 + c2 * 64 + w * 16 + ln) * QKV_LD
                                    + qoff + hf * 32 + qd * 8);

  auto stageK = [&](int kt, int buf) {
    #pragma unroll
    for (int c = 0; c < 2; ++c) {
      int sbase = c * 256 + w * 64;        // wave-uniform slot base
      int s = sbase + lane;
      int row = s >> 3, sub = (s & 7) ^ (row & 7);   // pre-swizzled source
      gld16(qkv + (tokbase + kt * 64 + row) * QKV_LD + koff + sub * 8,
            &sK[buf][sbase * 8]);
    }
  };
  auto loadV = [&](int kt, uint4& va, uint4& vb) {
    int tp = tid & 31, d0 = (tid >> 5) * 8;
    const u16* g0 = qkv + (tokbase + kt * 64 + tp * 2) * QKV_LD + voff + d0;
    va = *(const uint4*)g0;
    vb = *(const uint4*)(g0 + QKV_LD);
  };
  auto writeV = [&](u32* vbuf, const uint4& va, const uint4& vb) {
    int tp = tid & 31, d0 = (tid >> 5) * 8;  // d0 multiple of 8
    const u32* a  = (const u32*)&va;
    const u32* bb = (const u32*)&vb;
    #pragma unroll
    for (int e = 0; e < 4; ++e) {
      vbuf[(d0 + 2 * e    ) * 32 + (tp ^ (e << 3)    )] =
          __builtin_amdgcn_perm(bb[e], a[e], 0x05040100u);
      vbuf[(d0 + 2 * e + 1) * 32 + (tp ^ (e << 3) ^ 4)] =
          __builtin_amdgcn_perm(bb[e], a[e], 0x07060302u);
    }
  };

  f32x4 accOT[2][4] = {};          // O^T per chain: row d=ob*16+qd*4+r, col=ln
  f32x4 stA[4][2], stB[4][2];      // pipelined QK^T results (2 tiles in flight)
  float psum[2] = {0.f, 0.f};
  const int tsw = (ln & 7) << 2;   // sVT read-side XOR swizzle (u32 units)
  const int ksw = (ln & 7) << 3;   // sK read-side XOR swizzle (u16 units)

  auto qk_phase = [&](int t, f32x4 (&stW)[4][2]) {
    const int cur = t & 1;
    #pragma unroll
    for (int cb = 0; cb < 4; ++cb) {
      bf16x8 ak0 = *(const bf16x8*)&sK[cur][(cb * 16 + ln) * 64 + ((qd * 8) ^ ksw)];
      bf16x8 ak1 = *(const bf16x8*)&sK[cur][(cb * 16 + ln) * 64 + ((32 + qd * 8) ^ ksw)];
      #pragma unroll
      for (int c2 = 0; c2 < 2; ++c2) {
        f32x4 z = {0.f, 0.f, 0.f, 0.f};
        f32x4 t0 = __builtin_amdgcn_mfma_f32_16x16x32_bf16(ak0, aq[c2][0], z, 0, 0, 0);
        stW[cb][c2] = __builtin_amdgcn_mfma_f32_16x16x32_bf16(ak1, aq[c2][1], t0, 0, 0, 0);
      }
    }
  };
  auto fin_phase = [&](f32x4 (&stR)[4][2], const u32* vP) {
    #pragma unroll
    for (int cb = 0; cb < 4; ++cb) {
      s16x4 pf[2];
      #pragma unroll
      for (int c2 = 0; c2 < 2; ++c2) {
        float p0 = __builtin_amdgcn_exp2f(stR[cb][c2][0]);
        float p1 = __builtin_amdgcn_exp2f(stR[cb][c2][1]);
        float p2 = __builtin_amdgcn_exp2f(stR[cb][c2][2]);
        float p3 = __builtin_amdgcn_exp2f(stR[cb][c2][3]);
        psum[c2] += (p0 + p1) + (p2 + p3);
        union { u32 d[2]; s16x4 v; } pk;
        pk.d[0] = pkbf16(p0, p1);        // v_cvt_pk_bf16_f32
        pk.d[1] = pkbf16(p2, p3);
        pf[c2] = pk.v;
      }
      #pragma unroll
      for (int ob = 0; ob < 4; ++ob) {
        s16x4 vf = *(const s16x4*)&vP[(ob * 16 + ln) * 32 + ((cb * 8 + qd * 2) ^ tsw)];
        accOT[0][ob] = MFMA16(vf, pf[0], accOT[0][ob]);
        accOT[1][ob] = MFMA16(vf, pf[1], accOT[1][ob]);
      }
    }
  };

  // prologue: K(0) async; V(0) -> ring buf0; V(1) -> regs
  stageK(0, 0);
  uint4 va, vb;
  loadV(0, va, vb);
  writeV(sVT0, va, vb);
  loadV(1, va, vb);
  u32 *vPrev = sVT2, *vCur = sVT0, *vNext = sVT1;

  // t = 0 (no finish)
  __syncthreads();
  stageK(1, 1);
  writeV(vNext, va, vb);      // V(1)
  loadV(2, va, vb);
  qk_phase(0, stA);
  { u32* t = vPrev; vPrev = vCur; vCur = vNext; vNext = t; }

  // t = 1..30 in ping-pong pairs
  for (int S = 0; S < 15; ++S) {
    const int t1 = 2 * S + 1;
    __syncthreads();
    stageK(t1 + 1, (t1 + 1) & 1);
    writeV(vNext, va, vb);    // V(t1+1)
    loadV(t1 + 2, va, vb);    // t1 <= 29 -> t1+2 <= 31, always valid
    qk_phase(t1, stB);
    fin_phase(stA, vPrev);
    { u32* t = vPrev; vPrev = vCur; vCur = vNext; vNext = t; }
    const int t2 = t1 + 1;
    __syncthreads();
    stageK(t2 + 1, (t2 + 1) & 1);
    writeV(vNext, va, vb);    // V(t2+1)
    if (t2 < 30) loadV(t2 + 2, va, vb);
    qk_phase(t2, stA);
    fin_phase(stB, vPrev);
    { u32* t = vPrev; vPrev = vCur; vCur = vNext; vNext = t; }
  }

  // t = 31: QK -> stB, finish stA; then drain finish(31)
  __syncthreads();
  qk_phase(31, stB);
  fin_phase(stA, vPrev);      // tile 30
  fin_phase(stB, vCur);       // tile 31 (V(31) in vCur)

  // row-sum completion: reduce across the 4 quads
  #pragma unroll
  for (int c2 = 0; c2 < 2; ++c2) {
    float s = psum[c2];
    s += __shfl_xor(s, 16, 64);
    s += __shfl_xor(s, 32, 64);
    psum[c2] = 1.0f / s;
  }

  // transpose O^T -> O through LDS (reuse smem), coalesced bf16 stores
  u16* sOut = smem;                      // [128 tokens][72] u16 = 18 KB
  __syncthreads();
  #pragma unroll
  for (int c2 = 0; c2 < 2; ++c2)
    #pragma unroll
    for (int ob = 0; ob < 4; ++ob) {
      u32 lo = pkbf16(accOT[c2][ob][0] * psum[c2], accOT[c2][ob][1] * psum[c2]);
      u32 hi = pkbf16(accOT[c2][ob][2] * psum[c2], accOT[c2][ob][3] * psum[c2]);
      ((u32*)sOut)[(c2 * 64 + w * 16 + ln) * 36 + ob * 8 + qd * 2    ] = lo;
      ((u32*)sOut)[(c2 * 64 + w * 16 + ln) * 36 + ob * 8 + qd * 2 + 1] = hi;
    }
  __syncthreads();
  #pragma unroll
  for (int it = 0; it < 4; ++it) {
    int idx = it * 256 + tid;            // 0..1023
    int token = idx >> 3, chunk = idx & 7;
    uint4 v = *(const uint4*)&sOut[token * 72 + chunk * 8];
    *(uint4*)&outb[(tokbase + q0 + token) * D_MODEL + h * HD + chunk * 8] = v;
  }
}

// ---------- launch ----------
extern "C" void kernel_launch(void* const* d_in, const int* in_sizes, int n_in,
                              void* d_out, int out_size, void* d_ws, size_t ws_size,
                              hipStream_t stream) {
  const float* x      = (const float*)d_in[0];   // [4096,1024]
  const float* w_qkv  = (const float*)d_in[1];   // [3072,1024]
  const float* w_proj = (const float*)d_in[2];   // [1024,1024]
  const float* b_proj = (const float*)d_in[3];   // [1024]
  float* out = (float*)d_out;                    // [4096,1024]

  u16* ws     = (u16*)d_ws;
  u16* xb     = ws;                                   // 4096*1024
  u16* wqkvb  = xb    + (size_t)4096 * 1024;          // 3072*1024
  u16* wprojb = wqkvb + (size_t)3072 * 1024;          // 1024*1024
  u16* qkvb   = wprojb + (size_t)1024 * 1024;         // 4096*3072
  u16* attnb  = qkvb  + (size_t)4096 * 3072;          // 4096*1024

  // one fused cast: dst regions xb|wqkvb|wprojb are contiguous
  cast3_bf16<<<8192, 256, 0, stream>>>(x, w_qkv, w_proj, xb);

  // qkv = x @ w_qkv^T -> [4096,3072] bf16 (Q pre-scaled); 768 blocks = 3/CU
  gemm_nt<0, 128><<<dim3(24, 32), 256, 0, stream>>>(xb, wqkvb, qkvb, nullptr, nullptr, 3072, 1024);

  // attention -> [4096,1024] bf16; 512 blocks x 256 threads, 2/CU
  // 1-D grid: bid = qp*32 + bh so all qp-blocks of a (b,h) share an XCD
  attn_kernel<<<512, 256, 0, stream>>>(qkvb, attnb);

  // out = attn @ w_proj^T + b_proj -> fp32; 64x128 tiles, 512 blocks
  gemm_nt<1, 64><<<dim3(8, 64), 256, 0, stream>>>(attnb, wprojb, nullptr, out, b_proj, 1024, 1024);
}